// Round 8
// baseline (76.998 us; speedup 1.0000x reference)
//
#include <hip/hip_runtime.h>

// Problem constants (from reference)
#define BATCH     4096
#define N_CTX     8
#define N_TGT     16
#define NUM_DOCS  500
#define NUM_WORDS 8000
#define VEC_DIM   128
#define N_TILES   ((NUM_WORDS / 32) * (VEC_DIM / 32))  // 1000
#define NBLOCKS   (BATCH / 8)                          // 512 = 2 blocks/CU exactly
#define SPIN_LIMIT 50000                               // ~2-5 ms worst case, then fallback

// Native clang vector type (accepted by __builtin_nontemporal_load).
typedef float floatx4 __attribute__((ext_vector_type(4)));

// ---------------------------------------------------------------------------
// Single fused kernel, manual grid barrier:
//  phase A: issue O-tile loads (2 tiles/block)
//  phase B: issue D/W gather loads (nontemporal D)
//  phase C: LDS transpose -> OT rows (overlaps gather latency)
//  phase D: acc = sum_c D+W  (stays in REGISTERS across the barrier)
//  barrier: __syncthreads (drains stores) -> RELEASE fetch_add(ctr) ->
//           spin ACQUIRE load until ctr==NBLOCKS (bounded; timeout -> slow path)
//  phase E: 16 OT-row reads/half-wave (fast) or direct O-column scalars (slow,
//           correct without OT), segmented 16-shuffle multi-target reduction,
//           coalesced store.
// Removes: 2nd dispatch, X round-trip. 512 blocks @ launch_bounds(256,2) are
// fully co-resident (2/CU x 256 CU), so the barrier releases promptly.
// ---------------------------------------------------------------------------
__global__ __launch_bounds__(256, 2) void fused_barrier(
    const int* __restrict__ ctx, const int* __restrict__ docs,
    const int* __restrict__ tgt, const float* __restrict__ D,
    const float* __restrict__ W, const float* __restrict__ O,
    float* __restrict__ OT, unsigned int* __restrict__ ctr,
    float* __restrict__ out) {
  const int tid  = threadIdx.x;
  const int wave = tid >> 6;
  const int lane = tid & 63;
  const int hl   = lane & 31;
  const int b = (blockIdx.x * 4 + wave) * 2 + (lane >> 5);  // 8 batches/block

  __shared__ float tile[2][32][33];  // +1 pad: conflict-free
  __shared__ int sh_ok;
  const int tx = tid & 31;
  const int ty = tid >> 5;  // 0..7

  // ---- phase A: O-tile loads ----
  float r[2][4];
  int wB[2], vB[2], tok[2];
#pragma unroll
  for (int s = 0; s < 2; ++s) {
    const int ti = blockIdx.x * 2 + s;  // 0..1023; 1000 real tiles
    tok[s] = (ti < N_TILES);
    wB[s] = (ti % (NUM_WORDS / 32)) * 32;
    vB[s] = (ti / (NUM_WORDS / 32)) * 32;
    if (tok[s]) {
#pragma unroll
      for (int i = 0; i < 4; ++i)
        r[s][i] = O[(size_t)(vB[s] + ty + 8 * i) * NUM_WORDS + (wB[s] + tx)];
    }
  }

  // ---- phase B: D/W gather issue ----
  const int4 c0 = *(const int4*)(ctx + b * N_CTX);
  const int4 c1 = *(const int4*)(ctx + b * N_CTX + 4);
  const int  doc = docs[b];
  const int cw[N_CTX] = {c0.x, c0.y, c0.z, c0.w, c1.x, c1.y, c1.z, c1.w};
  const int4 t0 = *(const int4*)(tgt + b * N_TGT);
  const int4 t1 = *(const int4*)(tgt + b * N_TGT + 4);
  const int4 t2 = *(const int4*)(tgt + b * N_TGT + 8);
  const int4 t3 = *(const int4*)(tgt + b * N_TGT + 12);
  const int tw[N_TGT] = {t0.x, t0.y, t0.z, t0.w, t1.x, t1.y, t1.z, t1.w,
                         t2.x, t2.y, t2.z, t2.w, t3.x, t3.y, t3.z, t3.w};

  const float* Dbase = D + (size_t)doc * (NUM_WORDS * VEC_DIM) + 4 * hl;
  const float* Wbase = W + 4 * hl;
  floatx4 dd[N_CTX], ww[N_CTX];
#pragma unroll
  for (int c = 0; c < N_CTX; ++c) {
    dd[c] = __builtin_nontemporal_load(
        (const floatx4*)(Dbase + (size_t)cw[c] * VEC_DIM));
    ww[c] = *(const floatx4*)(Wbase + (size_t)cw[c] * VEC_DIM);
  }

  // ---- phase C: LDS transpose -> OT (overlaps gather latency) ----
#pragma unroll
  for (int s = 0; s < 2; ++s) {
    if (tok[s]) {
#pragma unroll
      for (int i = 0; i < 4; ++i) tile[s][ty + 8 * i][tx] = r[s][i];
    }
  }
  __syncthreads();
#pragma unroll
  for (int s = 0; s < 2; ++s) {
    if (tok[s]) {
#pragma unroll
      for (int i = 0; i < 4; ++i)
        OT[(size_t)(wB[s] + ty + 8 * i) * VEC_DIM + (vB[s] + tx)] =
            tile[s][tx][ty + 8 * i];
    }
  }

  // ---- phase D: accumulate (registers; carried across barrier) ----
  floatx4 acc = {0.f, 0.f, 0.f, 0.f};
#pragma unroll
  for (int c = 0; c < N_CTX; ++c) acc += dd[c] + ww[c];

  // ---- grid barrier: release OT, wait for all blocks ----
  __syncthreads();  // drains this block's OT stores (vmcnt) before signaling
  if (tid == 0) {
    __hip_atomic_fetch_add(ctr, 1u, __ATOMIC_RELEASE, __HIP_MEMORY_SCOPE_AGENT);
    unsigned int v;
    int it = 0;
    do {
      v = __hip_atomic_load(ctr, __ATOMIC_ACQUIRE, __HIP_MEMORY_SCOPE_AGENT);
      if (v >= (unsigned)NBLOCKS) break;
      __builtin_amdgcn_s_sleep(1);
    } while (++it < SPIN_LIMIT);
    sh_ok = (v >= (unsigned)NBLOCKS) ? 1 : 0;
  }
  __syncthreads();
  const bool fast = (sh_ok != 0);

  // ---- phase E: dot ----
  floatx4 o[N_TGT];
  if (fast) {
    const float* Obase = OT + 4 * hl;
#pragma unroll
    for (int t = 0; t < N_TGT; ++t)
      o[t] = *(const floatx4*)(Obase + (size_t)tw[t] * VEC_DIM);
  } else {
    // Fallback: direct O-column scalars (correct without OT; slow)
#pragma unroll
    for (int t = 0; t < N_TGT; ++t) {
      const float* Oc = O + tw[t] + (size_t)(4 * hl) * NUM_WORDS;
      o[t].x = Oc[0];
      o[t].y = Oc[NUM_WORDS];
      o[t].z = Oc[2 * NUM_WORDS];
      o[t].w = Oc[3 * NUM_WORDS];
    }
  }

  float p[N_TGT];
#pragma unroll
  for (int t = 0; t < N_TGT; ++t) {
    const floatx4 m = acc * o[t];
    p[t] = m.x + m.y + m.z + m.w;
  }

  // ---- segmented multi-target reduction within each 32-lane half ----
  const bool h4 = (lane & 16) != 0;
  float q[8];
#pragma unroll
  for (int t = 0; t < 8; ++t) {
    const float send = h4 ? p[t] : p[t + 8];
    const float recv = __shfl_xor(send, 16, 64);
    q[t] = (h4 ? p[t + 8] : p[t]) + recv;
  }
  const bool h3 = (lane & 8) != 0;
  float rr[4];
#pragma unroll
  for (int t = 0; t < 4; ++t) {
    const float send = h3 ? q[t] : q[t + 4];
    const float recv = __shfl_xor(send, 8, 64);
    rr[t] = (h3 ? q[t + 4] : q[t]) + recv;
  }
  const bool h2 = (lane & 4) != 0;
  float s2[2];
#pragma unroll
  for (int t = 0; t < 2; ++t) {
    const float send = h2 ? rr[t] : rr[t + 2];
    const float recv = __shfl_xor(send, 4, 64);
    s2[t] = (h2 ? rr[t + 2] : rr[t]) + recv;
  }
  const bool h1 = (lane & 2) != 0;
  float u;
  {
    const float send = h1 ? s2[0] : s2[1];
    const float recv = __shfl_xor(send, 2, 64);
    u = (h1 ? s2[1] : s2[0]) + recv;
  }
  u += __shfl_xor(u, 1, 64);

  if ((lane & 1) == 0) out[b * N_TGT + ((hl >> 1) & 15)] = u;
}

extern "C" void kernel_launch(void* const* d_in, const int* in_sizes, int n_in,
                              void* d_out, int out_size, void* d_ws, size_t ws_size,
                              hipStream_t stream) {
  const int*   ctx  = (const int*)d_in[0];    // (4096, 8)
  const int*   docs = (const int*)d_in[1];    // (4096,)
  const int*   tgt  = (const int*)d_in[2];    // (4096, 16)
  const float* D    = (const float*)d_in[3];  // (500, 8000, 128)
  const float* W    = (const float*)d_in[4];  // (8000, 128)
  const float* O    = (const float*)d_in[5];  // (128, 8000)
  float*       out  = (float*)d_out;          // (4096, 16)

  unsigned int* ctr = (unsigned int*)d_ws;                 // 4 B counter
  float* OT = (float*)((char*)d_ws + 1024);                // 4 MB, aligned

  hipMemsetAsync(ctr, 0, sizeof(unsigned int), stream);    // graph-capturable
  fused_barrier<<<dim3(NBLOCKS), dim3(256), 0, stream>>>(
      ctx, docs, tgt, D, W, O, OT, ctr, out);
}

// Round 9
// 16.209 us; speedup vs baseline: 4.7502x; 4.7502x over previous
//
#include <hip/hip_runtime.h>

// Problem constants (from reference)
#define BATCH     4096
#define N_CTX     8
#define N_TGT     16
#define NUM_DOCS  500
#define NUM_WORDS 8000
#define VEC_DIM   128
#define N_TILES   ((NUM_WORDS / 32) * (VEC_DIM / 32))  // 1000

// Native clang vector types.
typedef float          floatx4  __attribute__((ext_vector_type(4)));
typedef unsigned short ushortx4 __attribute__((ext_vector_type(4)));

__device__ __forceinline__ unsigned short f2bf(float f) {
  union { float f; unsigned int i; } v;
  v.f = f;
  // round-to-nearest-even
  const unsigned int r = v.i + 0x7FFFu + ((v.i >> 16) & 1u);
  return (unsigned short)(r >> 16);
}
__device__ __forceinline__ float bf2f(unsigned short u) {
  union { unsigned int i; float f; } v;
  v.i = ((unsigned int)u) << 16;
  return v.f;
}

// ---------------------------------------------------------------------------
// K1: D/W gather-sum -> X  ∥  transpose O -> OTb (bf16 rows).
// D/W gathers (longest HBM latency) issued first; the O-tile loads and LDS
// transpose run under that latency. 512 blocks: 2 tiles + 8 batches each.
// ---------------------------------------------------------------------------
__global__ __launch_bounds__(256, 2) void k1_gather_transpose(
    const int* __restrict__ ctx, const int* __restrict__ docs,
    const float* __restrict__ D, const float* __restrict__ W,
    const float* __restrict__ O, unsigned short* __restrict__ OTb,
    float* __restrict__ X) {
  const int tid  = threadIdx.x;
  const int wave = tid >> 6;
  const int lane = tid & 63;
  const int hl   = lane & 31;
  const int b = (blockIdx.x * 4 + wave) * 2 + (lane >> 5);  // 8 batches/block

  __shared__ float tile[2][32][33];  // +1 pad: conflict-free
  const int tx = tid & 31;
  const int ty = tid >> 5;  // 0..7

  // ---- phase A: issue D/W gather loads (longest latency first) ----
  const int4 c0 = *(const int4*)(ctx + b * N_CTX);
  const int4 c1 = *(const int4*)(ctx + b * N_CTX + 4);
  const int  doc = docs[b];
  const int cw[N_CTX] = {c0.x, c0.y, c0.z, c0.w, c1.x, c1.y, c1.z, c1.w};
  const float* Dbase = D + (size_t)doc * (NUM_WORDS * VEC_DIM) + 4 * hl;
  const float* Wbase = W + 4 * hl;
  floatx4 dd[N_CTX], ww[N_CTX];
#pragma unroll
  for (int c = 0; c < N_CTX; ++c) {
    // D has zero reuse (2 GB): stream past L2.
    dd[c] = __builtin_nontemporal_load(
        (const floatx4*)(Dbase + (size_t)cw[c] * VEC_DIM));
    ww[c] = *(const floatx4*)(Wbase + (size_t)cw[c] * VEC_DIM);
  }

  // ---- phase B: O-tile loads ----
  float r[2][4];
  int wB[2], vB[2], tok[2];
#pragma unroll
  for (int s = 0; s < 2; ++s) {
    const int ti = blockIdx.x * 2 + s;  // 0..1023; 1000 real tiles
    tok[s] = (ti < N_TILES);
    wB[s] = (ti % (NUM_WORDS / 32)) * 32;
    vB[s] = (ti / (NUM_WORDS / 32)) * 32;
    if (tok[s]) {
#pragma unroll
      for (int i = 0; i < 4; ++i)
        r[s][i] = O[(size_t)(vB[s] + ty + 8 * i) * NUM_WORDS + (wB[s] + tx)];
    }
  }

  // ---- phase C: LDS transpose -> OTb (bf16), overlaps gather latency ----
#pragma unroll
  for (int s = 0; s < 2; ++s) {
    if (tok[s]) {
#pragma unroll
      for (int i = 0; i < 4; ++i) tile[s][ty + 8 * i][tx] = r[s][i];
    }
  }
  __syncthreads();
#pragma unroll
  for (int s = 0; s < 2; ++s) {
    if (tok[s]) {
#pragma unroll
      for (int i = 0; i < 4; ++i)
        OTb[(size_t)(wB[s] + ty + 8 * i) * VEC_DIM + (vB[s] + tx)] =
            f2bf(tile[s][tx][ty + 8 * i]);
    }
  }

  // ---- phase D: accumulate and store X ----
  floatx4 acc = {0.f, 0.f, 0.f, 0.f};
#pragma unroll
  for (int c = 0; c < N_CTX; ++c) acc += dd[c] + ww[c];
  *(floatx4*)(X + (size_t)b * VEC_DIM + 4 * hl) = acc;
}

// ---------------------------------------------------------------------------
// K2: dot phase. One half-wave per batch; lane owns a 4-component v-slice.
// 16 bf16 OT rows (contiguous 256 B each, L2-hot; 8 B/lane loads) +
// segmented multi-target reduction: 16 sums per half in 16 shuffles.
// ---------------------------------------------------------------------------
__global__ __launch_bounds__(256, 2) void k2_dot(
    const int* __restrict__ tgt, const float* __restrict__ X,
    const unsigned short* __restrict__ OTb, float* __restrict__ out) {
  const int wave = threadIdx.x >> 6;
  const int lane = threadIdx.x & 63;
  const int hl   = lane & 31;
  const int b = (blockIdx.x * 4 + wave) * 2 + (lane >> 5);

  const int4 t0 = *(const int4*)(tgt + b * N_TGT);
  const int4 t1 = *(const int4*)(tgt + b * N_TGT + 4);
  const int4 t2 = *(const int4*)(tgt + b * N_TGT + 8);
  const int4 t3 = *(const int4*)(tgt + b * N_TGT + 12);
  const int tw[N_TGT] = {t0.x, t0.y, t0.z, t0.w, t1.x, t1.y, t1.z, t1.w,
                         t2.x, t2.y, t2.z, t2.w, t3.x, t3.y, t3.z, t3.w};

  const unsigned short* Obase = OTb + 4 * hl;
  ushortx4 o[N_TGT];
#pragma unroll
  for (int t = 0; t < N_TGT; ++t)
    o[t] = *(const ushortx4*)(Obase + (size_t)tw[t] * VEC_DIM);

  const floatx4 xv = *(const floatx4*)(X + (size_t)b * VEC_DIM + 4 * hl);

  float p[N_TGT];
#pragma unroll
  for (int t = 0; t < N_TGT; ++t) {
    p[t] = xv.x * bf2f(o[t].x) + xv.y * bf2f(o[t].y) +
           xv.z * bf2f(o[t].z) + xv.w * bf2f(o[t].w);
  }

  // segmented multi-target reduction within each 32-lane half
  const bool h4 = (lane & 16) != 0;
  float q[8];
#pragma unroll
  for (int t = 0; t < 8; ++t) {
    const float send = h4 ? p[t] : p[t + 8];
    const float recv = __shfl_xor(send, 16, 64);
    q[t] = (h4 ? p[t + 8] : p[t]) + recv;
  }
  const bool h3 = (lane & 8) != 0;
  float rr[4];
#pragma unroll
  for (int t = 0; t < 4; ++t) {
    const float send = h3 ? q[t] : q[t + 4];
    const float recv = __shfl_xor(send, 8, 64);
    rr[t] = (h3 ? q[t + 4] : q[t]) + recv;
  }
  const bool h2 = (lane & 4) != 0;
  float s2[2];
#pragma unroll
  for (int t = 0; t < 2; ++t) {
    const float send = h2 ? rr[t] : rr[t + 2];
    const float recv = __shfl_xor(send, 4, 64);
    s2[t] = (h2 ? rr[t + 2] : rr[t]) + recv;
  }
  const bool h1 = (lane & 2) != 0;
  float u;
  {
    const float send = h1 ? s2[0] : s2[1];
    const float recv = __shfl_xor(send, 2, 64);
    u = (h1 ? s2[1] : s2[0]) + recv;
  }
  u += __shfl_xor(u, 1, 64);

  if ((lane & 1) == 0) out[b * N_TGT + ((hl >> 1) & 15)] = u;
}

extern "C" void kernel_launch(void* const* d_in, const int* in_sizes, int n_in,
                              void* d_out, int out_size, void* d_ws, size_t ws_size,
                              hipStream_t stream) {
  const int*   ctx  = (const int*)d_in[0];    // (4096, 8)
  const int*   docs = (const int*)d_in[1];    // (4096,)
  const int*   tgt  = (const int*)d_in[2];    // (4096, 16)
  const float* D    = (const float*)d_in[3];  // (500, 8000, 128)
  const float* W    = (const float*)d_in[4];  // (8000, 128)
  const float* O    = (const float*)d_in[5];  // (128, 8000)
  float*       out  = (float*)d_out;          // (4096, 16)

  unsigned short* OTb = (unsigned short*)d_ws;                  // 2 MB (bf16)
  float* X = (float*)((char*)d_ws + (size_t)NUM_WORDS * VEC_DIM * 2);  // 2 MB

  k1_gather_transpose<<<dim3(BATCH / 8), dim3(256), 0, stream>>>(
      ctx, docs, D, W, O, OTb, X);
  k2_dot<<<dim3(BATCH / 8), dim3(256), 0, stream>>>(tgt, X, OTb, out);
}